// Round 1
// baseline (18603.856 us; speedup 1.0000x reference)
//
#include <hip/hip_runtime.h>

#define NSEQ   4096
#define TSTEPS 512
#define FIN    5
#define HID    64
#define SPB    4      // sequences per block
#define TCHUNK 64     // x-staging chunk (steps)

__device__ __forceinline__ float fast_sigmoid(float x) {
    return __builtin_amdgcn_rcpf(1.0f + __expf(-x));
}
__device__ __forceinline__ float fast_tanh(float x) {
    // tanh(x) = 1 - 2/(e^{2x}+1); correct limits at +/-inf via exp overflow/underflow
    return 1.0f - 2.0f * __builtin_amdgcn_rcpf(1.0f + __expf(2.0f * x));
}

// Block: 256 threads. Gate phase: thread = gate row g (k=g>>6 in {i,f,g,o}, u=g&63).
// Update phase: thread = (s = tid>>6, u = tid&63). Whh row lives in 64 VGPRs.
__global__ __launch_bounds__(256, 3)
void lstm_kernel(const float* __restrict__ feat,
                 const float* __restrict__ Wih,
                 const float* __restrict__ Whh,
                 const float* __restrict__ bih,
                 const float* __restrict__ bhh,
                 float* __restrict__ h_out) {
    __shared__ float h_lds[SPB][HID];          // current hidden state
    __shared__ float gates_lds[4][SPB][HID];   // activated gates
    __shared__ float x_lds[SPB * TCHUNK * FIN];

    const int tid = threadIdx.x;
    const int g   = tid;        // gate row
    const int k   = tid >> 6;   // gate class (wave-uniform)
    const int us  = tid >> 6;   // update-phase sequence
    const int uu  = tid & 63;   // unit
    const int seq0 = blockIdx.x * SPB;

    // Whh row -> registers (reused 512 steps)
    float Wr[HID];
#pragma unroll
    for (int j4 = 0; j4 < HID / 4; ++j4) {
        float4 w = *reinterpret_cast<const float4*>(&Whh[g * HID + j4 * 4]);
        Wr[j4 * 4 + 0] = w.x; Wr[j4 * 4 + 1] = w.y;
        Wr[j4 * 4 + 2] = w.z; Wr[j4 * 4 + 3] = w.w;
    }
    float wih_r[FIN];
#pragma unroll
    for (int f = 0; f < FIN; ++f) wih_r[f] = Wih[g * FIN + f];
    const float br = bih[g] + bhh[g];

    h_lds[us][uu] = 0.0f;   // covers all SPB*HID entries
    float c = 0.0f;
    __syncthreads();

    for (int t0 = 0; t0 < TSTEPS; t0 += TCHUNK) {
        // stage x chunk (coalesced; previous chunk's reads completed before
        // the end-of-step barrier of the prior iteration)
        for (int idx = tid; idx < SPB * TCHUNK * FIN; idx += 256) {
            int s   = idx / (TCHUNK * FIN);
            int off = idx - s * (TCHUNK * FIN);
            x_lds[idx] = feat[((size_t)(seq0 + s) * TSTEPS + t0) * FIN + off];
        }
        __syncthreads();

        for (int tt = 0; tt < TCHUNK; ++tt) {
            // ---- gate phase: acc[s] = b + Wih.x + Whh_row . h[s] ----
            float acc[SPB];
#pragma unroll
            for (int s = 0; s < SPB; ++s) {
                const float* xp = &x_lds[(s * TCHUNK + tt) * FIN];
                float a = br;
#pragma unroll
                for (int f = 0; f < FIN; ++f) a += wih_r[f] * xp[f];
                acc[s] = a;
            }
#pragma unroll
            for (int j4 = 0; j4 < HID / 4; ++j4) {
#pragma unroll
                for (int s = 0; s < SPB; ++s) {
                    float4 h4 = *reinterpret_cast<const float4*>(&h_lds[s][j4 * 4]);
                    acc[s] += Wr[j4 * 4 + 0] * h4.x;
                    acc[s] += Wr[j4 * 4 + 1] * h4.y;
                    acc[s] += Wr[j4 * 4 + 2] * h4.z;
                    acc[s] += Wr[j4 * 4 + 3] * h4.w;
                }
            }
#pragma unroll
            for (int s = 0; s < SPB; ++s) {
                float a   = acc[s];
                float act = (k == 2) ? fast_tanh(a) : fast_sigmoid(a); // wave-uniform branch
                gates_lds[k][s][uu] = act;
            }
            __syncthreads();

            // ---- update phase: c,h for (us, uu) ----
            float gi = gates_lds[0][us][uu];
            float gf = gates_lds[1][us][uu];
            float gg = gates_lds[2][us][uu];
            float go = gates_lds[3][us][uu];
            c = gf * c + gi * gg;
            float h = go * fast_tanh(c);
            h_lds[us][uu] = h;
            __syncthreads();
        }
    }
    h_out[(size_t)(seq0 + us) * HID + uu] = h_lds[us][uu];
}

// pred = leaky_relu(h_last @ Wd^T + bd); also zero the ws accumulators
__global__ void pred_kernel(const float* __restrict__ h_in,
                            const float* __restrict__ Wd,
                            const float* __restrict__ bd,
                            float* __restrict__ pred_out,
                            float* __restrict__ accums) {
    int n = blockIdx.x * blockDim.x + threadIdx.x;
    if (blockIdx.x == 0 && threadIdx.x < 4) accums[threadIdx.x] = 0.0f;
    const float* h = &h_in[(size_t)n * HID];
    float s = bd[0];
#pragma unroll
    for (int j4 = 0; j4 < HID / 4; ++j4) {
        float4 h4 = *reinterpret_cast<const float4*>(&h[j4 * 4]);
        s += Wd[j4 * 4 + 0] * h4.x + Wd[j4 * 4 + 1] * h4.y +
             Wd[j4 * 4 + 2] * h4.z + Wd[j4 * 4 + 3] * h4.w;
    }
    float p = (s >= 0.0f) ? s : 0.2f * s;
    pred_out[n] = p;
}

__global__ void regloss_kernel(const float* __restrict__ pred,
                               const float* __restrict__ ret,
                               const int* __restrict__ mask,
                               float* __restrict__ accums) {
    int n = blockIdx.x * blockDim.x + threadIdx.x;
    float m = (mask[n] != 0) ? 1.0f : 0.0f;
    float d = pred[n] - ret[n];
    float v = d * d * m;
#pragma unroll
    for (int off = 32; off > 0; off >>= 1) {
        v += __shfl_down(v, off, 64);
        m += __shfl_down(m, off, 64);
    }
    if ((threadIdx.x & 63) == 0) {
        atomicAdd(&accums[0], v);
        atomicAdd(&accums[1], m);
    }
}

// rank loss: 256 blocks x 16 i's each, 16-way j split per i; data staged in LDS
__global__ __launch_bounds__(256)
void rankloss_kernel(const float* __restrict__ pred,
                     const float* __restrict__ ret,
                     const int* __restrict__ mask,
                     float* __restrict__ accums) {
    __shared__ float sp[NSEQ];
    __shared__ float sg[NSEQ];
    __shared__ float sq[NSEQ];
    int tid = threadIdx.x;
    for (int idx = tid; idx < NSEQ; idx += 256) {
        sp[idx] = pred[idx];
        sg[idx] = ret[idx];
        sq[idx] = (mask[idx] != 0) ? 1.0f : 0.0f;
    }
    __syncthreads();

    int iloc = tid >> 4;       // 0..15
    int jp   = tid & 15;
    int i    = blockIdx.x * 16 + iloc;
    float pi = sp[i], gi = sg[i], qi = sq[i];
    float sum = 0.0f;
    for (int j = jp; j < NSEQ; j += 16) {
        float t = -(sp[j] - pi) * (sg[j] - gi);
        sum += fmaxf(t, 0.0f) * sq[j];
    }
    sum *= qi;
#pragma unroll
    for (int off = 32; off > 0; off >>= 1) sum += __shfl_down(sum, off, 64);
    __shared__ float wsum[4];
    if ((tid & 63) == 0) wsum[tid >> 6] = sum;
    __syncthreads();
    if (tid == 0) atomicAdd(&accums[2], wsum[0] + wsum[1] + wsum[2] + wsum[3]);
}

__global__ void final_kernel(const float* __restrict__ accums,
                             float* __restrict__ out) {
    float reg  = accums[0] / (accums[1] + 1e-8f);
    float rank = accums[2] / 16777216.0f;   // N*N
    out[NSEQ + 0] = reg + rank;
    out[NSEQ + 1] = reg;
    out[NSEQ + 2] = rank;
}

extern "C" void kernel_launch(void* const* d_in, const int* in_sizes, int n_in,
                              void* d_out, int out_size, void* d_ws, size_t ws_size,
                              hipStream_t stream) {
    const float* feat = (const float*)d_in[0];
    const float* ret  = (const float*)d_in[1];
    const int*   mask = (const int*)d_in[2];
    const float* Wih  = (const float*)d_in[3];
    const float* Whh  = (const float*)d_in[4];
    const float* bih  = (const float*)d_in[5];
    const float* bhh  = (const float*)d_in[6];
    const float* Wd   = (const float*)d_in[7];
    const float* bd   = (const float*)d_in[8];
    float* out    = (float*)d_out;
    float* accums = (float*)d_ws;            // [0..3] loss partials
    float* h_out  = (float*)d_ws + 16;       // [NSEQ][HID]

    lstm_kernel<<<NSEQ / SPB, 256, 0, stream>>>(feat, Wih, Whh, bih, bhh, h_out);
    pred_kernel<<<NSEQ / 256, 256, 0, stream>>>(h_out, Wd, bd, out, accums);
    regloss_kernel<<<NSEQ / 256, 256, 0, stream>>>(out, ret, mask, accums);
    rankloss_kernel<<<256, 256, 0, stream>>>(out, ret, mask, accums);
    final_kernel<<<1, 1, 0, stream>>>(accums, out);
}